// Round 6
// baseline (392.351 us; speedup 1.0000x reference)
//
#include <hip/hip_runtime.h>
#include <math.h>

// ---- problem constants ----
#define BB 16
#define FD 32          // F == C == 32
#define ND 200
#define TD 48
#define SD 3
#define OC 64
#define SLICE 6400            // N*C elements per (b,t)
#define TSTRIDE 4915200       // B*T*N*C elements per tensor
#define NEGBIG (-9.0e15f)

typedef __attribute__((ext_vector_type(8))) short bf16x8;
typedef __attribute__((ext_vector_type(4))) float f32x4;

// round-half-up bf16 (within 1 ulp of RNE, 1 VALU op + shift)
static __device__ __forceinline__ unsigned short f2bf(float f) {
  unsigned u = __builtin_bit_cast(unsigned, f);
  return (unsigned short)((u + 0x8000u) >> 16);
}
// exact RNE (used for hi/lo weight split so the residual is well-defined)
static __device__ __forceinline__ unsigned short f2bf_rne(float f) {
  unsigned u = __builtin_bit_cast(unsigned, f);
  return (unsigned short)((u + 0x7FFFu + ((u >> 16) & 1u)) >> 16);
}
static __device__ __forceinline__ float bf2f(unsigned short h) {
  unsigned u = ((unsigned)h) << 16;
  return __builtin_bit_cast(float, u);
}

// One prep launch, three block ranges:
//   [0,3200):      x (b,f,n,t) fp32 -> Xtnc (b,t,n,c) bf16 + Xntc (b,n,t,c) bf16
//   [3200,3824):   adjacency -> 200-bit row masks (208 rows/si, 32 B/row)
//   [3824,3976):   W transpose->bf16, w-vector hi/lo frags, mlp_w -> bf16
__global__ __launch_bounds__(256) void k_prep(
    const float* __restrict__ x, const int* __restrict__ support,
    const float* __restrict__ W1, const float* __restrict__ WK,
    const float* __restrict__ a1, const float* __restrict__ aK,
    const float* __restrict__ mw,
    unsigned short* __restrict__ Xtnc, unsigned short* __restrict__ Xntc,
    unsigned long long* __restrict__ msk,
    unsigned short* __restrict__ Wtb, unsigned short* __restrict__ Wxb,
    unsigned short* __restrict__ mwb) {
  __shared__ float sbuf[32 * 49];
  int bid = blockIdx.x;
  if (bid < 3200) {
    int b = bid / ND, n = bid % ND;
    float(*sf)[49] = (float(*)[49])sbuf;
    for (int i = threadIdx.x; i < 32 * 48; i += 256) {
      int f = i / 48, t = i % 48;
      sf[f][t] = x[((size_t)(b * 32 + f) * ND + n) * 48 + t];
    }
    __syncthreads();
    unsigned int* dt = (unsigned int*)Xtnc;
    unsigned int* dn = (unsigned int*)Xntc;
    for (int j = threadIdx.x; j < 768; j += 256) {
      int t = j >> 4, fq = j & 15;
      unsigned int v = (unsigned int)f2bf(sf[2 * fq][t]) |
                       ((unsigned int)f2bf(sf[2 * fq + 1][t]) << 16);
      dt[((size_t)(b * 48 + t) * ND + n) * 16 + fq] = v;
      dn[((size_t)(b * ND + n) * 48 + t) * 16 + fq] = v;
    }
  } else if (bid < 3824) {
    int q = bid - 3200;
    int si = q / 13, rg = q % 13;
    const int* adjb = support + (size_t)si * ND * ND;
    int wv = threadIdx.x >> 6, lane = threadIdx.x & 63;
#pragma unroll
    for (int j = 0; j < 4; j++) {
      int r = rg * 16 + wv * 4 + j;
      unsigned long long w0 = 0, w1 = 0, w2 = 0, w3 = 0;
      if (r < ND) {
        w0 = __ballot(adjb[r * ND + lane] > 0);
        w1 = __ballot(adjb[r * ND + 64 + lane] > 0);
        w2 = __ballot(((128 + lane < ND) ? adjb[r * ND + 128 + lane] : 0) > 0);
        w3 = __ballot(((192 + lane < ND) ? adjb[r * ND + 192 + lane] : 0) > 0);
      }
      unsigned long long o = w0;
      if (lane == 1) o = w1;
      if (lane == 2) o = w2;
      if (lane == 3) o = w3;
      if (lane < 4) msk[((size_t)si * 208 + r) * 4 + lane] = o;
    }
  } else {
    int b2 = bid - 3824;
    if (b2 < 96) {
      int mat = b2 >> 4, b = b2 & 15;
      const float* src = (mat < 3) ? (W1 + (size_t)(mat * 16 + b) * 1024)
                                   : (WK + (size_t)((mat - 3) * 16 + b) * 1024);
      const float* av = (mat < 3) ? (a1 + (size_t)mat * 1024 + b * 64)
                                  : (aK + (size_t)(mat - 3) * 1024 + b * 64);
      unsigned short* dst = Wtb + (size_t)b2 * 1024;
      for (int i = threadIdx.x; i < 1024; i += 256) {
        int c = i >> 5, f = i & 31;
        dst[c * 32 + f] = f2bf_rne(src[f * 32 + c]);
      }
      // w-vectors: w1 = W@a1cols, w2 = W@a2cols (fp32), hi/lo bf16 split
      if (threadIdx.x < 32) {
        int f = threadIdx.x;
        float s1 = 0.f, s2 = 0.f;
        for (int c = 0; c < 32; c++) {
          float wfc = src[f * 32 + c];
          s1 = fmaf(wfc, av[c], s1);
          s2 = fmaf(wfc, av[32 + c], s2);
        }
        sbuf[f] = s1;
        sbuf[32 + f] = s2;
      }
      __syncthreads();
      unsigned short* wx = Wxb + (size_t)b2 * 512;  // [col][f], 16x32
      for (int i = threadIdx.x; i < 512; i += 256) {
        int col = i >> 5, f = i & 31;
        unsigned short o = 0;
        if (col < 4) {
          float s = sbuf[(col >> 1) * 32 + f];
          unsigned short hi = f2bf_rne(s);
          o = (col & 1) ? f2bf_rne(s - bf2f(hi)) : hi;
        }
        wx[i] = o;
      }
    } else {
      int i = (b2 - 96) * 256 + threadIdx.x;
      if (i < OC * 224) mwb[i] = f2bf_rne(mw[i]);
    }
  }
}

// Fused double-hop GAT per (idx,b,t). Wh + f1/f2 via MFMA (f1/f2 through an
// extra B-frag holding hi/lo split of W@a vectors -> fp32-accurate, no shuffle
// chains); attention P@V via MFMA with per-k A-frag build (exp of masked
// lrelu), denominator via ones-B MFMA. All-masked rows -> uniform 1/200 *
// colsum(V) (JAX softmax of all -9e15). Hop1 out staged in LDS for hop2.
__global__ __launch_bounds__(256, 5) void k_gat2(
    const unsigned short* __restrict__ Xb,   // (b,t,n,c) bf16 (padded alloc)
    const unsigned short* __restrict__ Wtb,  // 6 mats: [mat][b][c][f] bf16
    const unsigned short* __restrict__ Wxb,  // 6 mats: [mat][b][16][32] bf16
    const unsigned char* __restrict__ mskb,  // (b*SD+idx)*208*32 bytes
    unsigned short* __restrict__ bfp) {      // 7-tensor bf16 (b,n,t,c) pool
  int bx = blockIdx.x;
  int idx = bx / (BB * TD);
  int bt = bx % (BB * TD);
  int b = bt / TD, t = bt % TD;
  __shared__ __align__(16) unsigned short Vt[32 * 232];   // [ch][m] pad->232
  __shared__ __align__(16) unsigned short Y1s[208 * 32];  // hop1 out [n][c]
  __shared__ __align__(16) float f2s[224];
  __shared__ float f1s[208];
  __shared__ float SVa[64];   // [0..31] hop1 colsum, [32..63] hop2
  int tid = threadIdx.x, w = tid >> 6, lane = tid & 63;
  int cl = lane & 15, qd = lane >> 4;

  // ---- init pads ----
  if (tid < 64) SVa[tid] = 0.f;
  if (tid >= 200 && tid < 224) {
    f2s[tid] = 0.f;
    if (tid < 208) f1s[tid] = 0.f;
  }
  for (int i = tid; i < 512; i += 256) {  // Vt[:][200..231] = 0
    int cch = i >> 4, d = i & 15;
    ((unsigned int*)&Vt[cch * 232 + 200])[d] = 0u;
  }
  for (int i = tid; i < 128; i += 256)    // Y1s rows 200..207 = 0
    ((unsigned int*)&Y1s[200 * 32])[i] = 0u;
  __syncthreads();

  const unsigned char* mrow = mskb + (size_t)(b * SD + idx) * 208 * 32;
  bf16x8 ones;
#pragma unroll
  for (int j = 0; j < 8; j++) ones[j] = (short)0x3F80;  // bf16 1.0
  size_t xbase = (size_t)bt * SLICE;
  unsigned short* Yb1 = bfp + (size_t)(1 + 2 * idx) * TSTRIDE;
  unsigned short* Yb2 = bfp + (size_t)(2 + 2 * idx) * TSTRIDE;

#pragma unroll
  for (int hop = 0; hop < 2; hop++) {
    int mat = (hop == 0) ? idx : (3 + idx);
    const unsigned short* wtb = Wtb + (size_t)(mat * 16 + b) * 1024;
    const unsigned short* wxb = Wxb + (size_t)(mat * 16 + b) * 512;
    bf16x8 Bw0 = *(const bf16x8*)(wtb + cl * 32 + qd * 8);
    bf16x8 Bw1 = *(const bf16x8*)(wtb + (cl + 16) * 32 + qd * 8);
    bf16x8 Bwx = *(const bf16x8*)(wxb + cl * 32 + qd * 8);
    float* SV = SVa + hop * 32;

    // ---- Wh phase ----
    for (int ti = w; ti < 13; ti += 4) {
      bf16x8 A;
      if (hop == 0)
        A = *(const bf16x8*)(Xb + xbase + (size_t)(ti * 16 + cl) * 32 + qd * 8);
      else
        A = *(const bf16x8*)&Y1s[(ti * 16 + cl) * 32 + qd * 8];
      f32x4 d0 = {0.f, 0.f, 0.f, 0.f}, d1 = d0, d2 = d0;
      d0 = __builtin_amdgcn_mfma_f32_16x16x32_bf16(A, Bw0, d0, 0, 0, 0);
      d1 = __builtin_amdgcn_mfma_f32_16x16x32_bf16(A, Bw1, d1, 0, 0, 0);
      d2 = __builtin_amdgcn_mfma_f32_16x16x32_bf16(A, Bwx, d2, 0, 0, 0);
      float s0 = 0.f, s1 = 0.f;
#pragma unroll
      for (int r = 0; r < 4; r++) {
        float fv = d2[r] + __shfl_xor(d2[r], 1, 64);  // cl0:f1, cl2:f2
        int rn = ti * 16 + qd * 4 + r;
        if (rn < ND) {
          Vt[cl * 232 + rn] = f2bf(d0[r]);
          Vt[(cl + 16) * 232 + rn] = f2bf(d1[r]);
          s0 += d0[r];
          s1 += d1[r];
          if (cl == 0) f1s[rn] = fv;
          if (cl == 2) f2s[rn] = fv;
        }
      }
      atomicAdd(&SV[cl], s0);
      atomicAdd(&SV[cl + 16], s1);
    }
    __syncthreads();

    // ---- attention phase ----
    for (int ti = w; ti < 13; ti += 4) {
      int row = ti * 16 + cl;
      float f1v = f1s[row];
      const unsigned char* mrp = mrow + row * 32 + qd;
      f32x4 denom = {0.f, 0.f, 0.f, 0.f};
      f32x4 acc0 = denom, acc1 = denom;
#pragma unroll
      for (int k = 0; k < 7; k++) {
        int m0 = k * 32 + qd * 8;
        bf16x8 b0 = *(const bf16x8*)&Vt[cl * 232 + m0];
        bf16x8 b1 = *(const bf16x8*)&Vt[(cl + 16) * 232 + m0];
        float4 fa = *(const float4*)&f2s[m0];
        float4 fb = *(const float4*)&f2s[m0 + 4];
        unsigned int mby = mrp[k * 4];
        float ev[8];
        ev[0] = fa.x; ev[1] = fa.y; ev[2] = fa.z; ev[3] = fa.w;
        ev[4] = fb.x; ev[5] = fb.y; ev[6] = fb.z; ev[7] = fb.w;
        bf16x8 A;
#pragma unroll
        for (int j = 0; j < 8; j++) {
          float e = f1v + ev[j];
          e = fmaxf(e, 0.2f * e);                 // leaky_relu alpha=0.2
          e = ((mby >> j) & 1u) ? e : NEGBIG;     // mask -> exp()==0
          A[j] = (short)f2bf(__expf(e));
        }
        denom = __builtin_amdgcn_mfma_f32_16x16x32_bf16(A, ones, denom, 0, 0, 0);
        acc0 = __builtin_amdgcn_mfma_f32_16x16x32_bf16(A, b0, acc0, 0, 0, 0);
        acc1 = __builtin_amdgcn_mfma_f32_16x16x32_bf16(A, b1, acc1, 0, 0, 0);
      }
#pragma unroll
      for (int r = 0; r < 4; r++) {
        int rn = ti * 16 + qd * 4 + r;
        if (rn < ND) {
          float dn = denom[r];
          float v0, v1;
          if (dn > 0.f) {
            float iv = 1.0f / dn;
            v0 = acc0[r] * iv;
            v1 = acc1[r] * iv;
          } else {
            v0 = SV[cl] * (1.0f / ND);
            v1 = SV[cl + 16] * (1.0f / ND);
          }
          if (hop == 0) {
            v0 = (v0 > 0.f) ? v0 : __expf(v0) - 1.f;  // elu
            v1 = (v1 > 0.f) ? v1 : __expf(v1) - 1.f;
            unsigned short h0 = f2bf(v0), h1 = f2bf(v1);
            Y1s[rn * 32 + cl] = h0;
            Y1s[rn * 32 + cl + 16] = h1;
            size_t yb = ((size_t)(b * ND + rn) * TD + t) * 32;
            Yb1[yb + cl] = h0;
            Yb1[yb + cl + 16] = h1;
          } else {
            v0 = fmaxf(v0, 0.f);  // relu (== relu(elu(h)))
            v1 = fmaxf(v1, 0.f);
            size_t yb = ((size_t)(b * ND + rn) * TD + t) * 32;
            Yb2[yb + cl] = f2bf(v0);
            Yb2[yb + cl + 16] = f2bf(v1);
          }
        }
      }
    }
    if (hop == 0) __syncthreads();
  }
}

// 1x1 conv as MFMA GEMM per (b,n): OUT[t,o] = H[t,c] @ mw^T[c,o].
__global__ __launch_bounds__(192) void k_conv(
    const unsigned short* __restrict__ hb,   // 7 bf16 (b,n,t,c), stride TSTRIDE
    const unsigned short* __restrict__ mwb,  // (64,224) bf16
    const float* __restrict__ mb,
    float* __restrict__ out) {
  int bn = blockIdx.x;
  int b = bn / ND, n = bn % ND;
  int w = threadIdx.x >> 6, lane = threadIdx.x & 63;
  int cl = lane & 15, qd = lane >> 4;
  int mt = w;  // M-tile (t-range mt*16..mt*16+15)
  size_t abase = ((size_t)(b * ND + n) * TD + mt * 16 + cl) * 32 + qd * 8;
  bf16x8 A[7];
#pragma unroll
  for (int k = 0; k < 7; k++)
    A[k] = *(const bf16x8*)(hb + (size_t)k * TSTRIDE + abase);
#pragma unroll
  for (int nt = 0; nt < 4; nt++) {
    f32x4 acc = {0.f, 0.f, 0.f, 0.f};
#pragma unroll
    for (int k = 0; k < 7; k++) {
      bf16x8 bw = *(const bf16x8*)(mwb + (size_t)(nt * 16 + cl) * 224 + k * 32 + qd * 8);
      acc = __builtin_amdgcn_mfma_f32_16x16x32_bf16(A[k], bw, acc, 0, 0, 0);
    }
    int o = nt * 16 + cl;
    float bias = mb[o];
    float4 st;
    st.x = acc[0] + bias;
    st.y = acc[1] + bias;
    st.z = acc[2] + bias;
    st.w = acc[3] + bias;
    *(float4*)(out + ((size_t)(b * OC + o) * ND + n) * TD + mt * 16 + qd * 4) = st;
  }
}

extern "C" void kernel_launch(void* const* d_in, const int* in_sizes, int n_in,
                              void* d_out, int out_size, void* d_ws, size_t ws_size,
                              hipStream_t stream) {
  const float* x = (const float*)d_in[0];
  const int* support = (const int*)d_in[1];
  const float* W1 = (const float*)d_in[2];
  const float* a1 = (const float*)d_in[3];
  const float* WK = (const float*)d_in[4];
  const float* aK = (const float*)d_in[5];
  const float* mw = (const float*)d_in[6];
  const float* mb = (const float*)d_in[7];
  float* out = (float*)d_out;
  char* wsb = (char*)d_ws;
  // ws layout (bytes):
  //   Xbt bf16 (b,t,n,c) +1KB pad  @ 0            9,831,424
  //   bfp 7x bf16 (b,n,t,c)        @  9,831,424  68,812,800
  //   msk 48*208*32 B              @ 78,644,224     319,488
  //   mwb bf16                     @ 78,963,712      28,672
  //   Wtb 6*16*1024 bf16           @ 78,992,384     196,608
  //   Wxb 6*16*512  bf16           @ 79,188,992      98,304   => ~79.3 MB
  unsigned short* Xbt = (unsigned short*)wsb;
  unsigned short* bfp = (unsigned short*)(wsb + 9831424);
  unsigned char* msk = (unsigned char*)(wsb + 78644224);
  unsigned short* mwb = (unsigned short*)(wsb + 78963712);
  unsigned short* Wtb = (unsigned short*)(wsb + 78992384);
  unsigned short* Wxb = (unsigned short*)(wsb + 79188992);

  k_prep<<<3976, 256, 0, stream>>>(x, support, W1, WK, a1, aK, mw, Xbt, bfp,
                                   (unsigned long long*)msk, Wtb, Wxb, mwb);
  k_gat2<<<SD * BB * TD, 256, 0, stream>>>(Xbt, Wtb, Wxb, msk, bfp);
  k_conv<<<BB * ND, 192, 0, stream>>>(bfp, mwb, mb, out);
}

// Round 7
// 318.205 us; speedup vs baseline: 1.2330x; 1.2330x over previous
//
#include <hip/hip_runtime.h>
#include <math.h>

// ---- problem constants ----
#define BB 16
#define FD 32          // F == C == 32
#define ND 200
#define TD 48
#define SD 3
#define OC 64
#define SLICE 6400            // N*C elements per (b,t)
#define TSTRIDE 4915200       // B*T*N*C elements per tensor
#define NEGBIG (-9.0e15f)

typedef __attribute__((ext_vector_type(8))) short bf16x8;
typedef __attribute__((ext_vector_type(4))) float f32x4;

// round-half-up bf16 (within 1 ulp of RNE, 1 VALU op + shift)
static __device__ __forceinline__ unsigned short f2bf(float f) {
  unsigned u = __builtin_bit_cast(unsigned, f);
  return (unsigned short)((u + 0x8000u) >> 16);
}
// exact RNE (used for hi/lo weight split so the residual is well-defined)
static __device__ __forceinline__ unsigned short f2bf_rne(float f) {
  unsigned u = __builtin_bit_cast(unsigned, f);
  return (unsigned short)((u + 0x7FFFu + ((u >> 16) & 1u)) >> 16);
}
static __device__ __forceinline__ float bf2f(unsigned short h) {
  unsigned u = ((unsigned)h) << 16;
  return __builtin_bit_cast(float, u);
}

// One prep launch, three block ranges:
//   [0,3200):      x (b,f,n,t) fp32 -> Xtnc (b,t,n,c) bf16 + Xntc (b,n,t,c) bf16
//   [3200,3824):   adjacency -> 200-bit row masks (208 rows/si, 32 B/row)
//   [3824,3976):   W transpose->bf16, w-vector hi/lo frags, mlp_w -> bf16
__global__ __launch_bounds__(256) void k_prep(
    const float* __restrict__ x, const int* __restrict__ support,
    const float* __restrict__ W1, const float* __restrict__ WK,
    const float* __restrict__ a1, const float* __restrict__ aK,
    const float* __restrict__ mw,
    unsigned short* __restrict__ Xtnc, unsigned short* __restrict__ Xntc,
    unsigned long long* __restrict__ msk,
    unsigned short* __restrict__ Wtb, unsigned short* __restrict__ Wxb,
    unsigned short* __restrict__ mwb) {
  __shared__ float sbuf[32 * 49];
  int bid = blockIdx.x;
  if (bid < 3200) {
    int b = bid / ND, n = bid % ND;
    float(*sf)[49] = (float(*)[49])sbuf;
    for (int i = threadIdx.x; i < 32 * 48; i += 256) {
      int f = i / 48, t = i % 48;
      sf[f][t] = x[((size_t)(b * 32 + f) * ND + n) * 48 + t];
    }
    __syncthreads();
    unsigned int* dt = (unsigned int*)Xtnc;
    unsigned int* dn = (unsigned int*)Xntc;
    for (int j = threadIdx.x; j < 768; j += 256) {
      int t = j >> 4, fq = j & 15;
      unsigned int v = (unsigned int)f2bf(sf[2 * fq][t]) |
                       ((unsigned int)f2bf(sf[2 * fq + 1][t]) << 16);
      dt[((size_t)(b * 48 + t) * ND + n) * 16 + fq] = v;
      dn[((size_t)(b * ND + n) * 48 + t) * 16 + fq] = v;
    }
  } else if (bid < 3824) {
    int q = bid - 3200;
    int si = q / 13, rg = q % 13;
    const int* adjb = support + (size_t)si * ND * ND;
    int wv = threadIdx.x >> 6, lane = threadIdx.x & 63;
#pragma unroll
    for (int j = 0; j < 4; j++) {
      int r = rg * 16 + wv * 4 + j;
      unsigned long long w0 = 0, w1 = 0, w2 = 0, w3 = 0;
      if (r < ND) {
        w0 = __ballot(adjb[r * ND + lane] > 0);
        w1 = __ballot(adjb[r * ND + 64 + lane] > 0);
        w2 = __ballot(((128 + lane < ND) ? adjb[r * ND + 128 + lane] : 0) > 0);
        w3 = __ballot(((192 + lane < ND) ? adjb[r * ND + 192 + lane] : 0) > 0);
      }
      unsigned long long o = w0;
      if (lane == 1) o = w1;
      if (lane == 2) o = w2;
      if (lane == 3) o = w3;
      if (lane < 4) msk[((size_t)si * 208 + r) * 4 + lane] = o;
    }
  } else {
    int b2 = bid - 3824;
    if (b2 < 96) {
      int mat = b2 >> 4, b = b2 & 15;
      const float* src = (mat < 3) ? (W1 + (size_t)(mat * 16 + b) * 1024)
                                   : (WK + (size_t)((mat - 3) * 16 + b) * 1024);
      const float* av = (mat < 3) ? (a1 + (size_t)mat * 1024 + b * 64)
                                  : (aK + (size_t)(mat - 3) * 1024 + b * 64);
      unsigned short* dst = Wtb + (size_t)b2 * 1024;
      for (int i = threadIdx.x; i < 1024; i += 256) {
        int c = i >> 5, f = i & 31;
        dst[c * 32 + f] = f2bf_rne(src[f * 32 + c]);
      }
      // w-vectors: w1 = W@a1cols, w2 = W@a2cols (fp32), hi/lo bf16 split
      if (threadIdx.x < 32) {
        int f = threadIdx.x;
        float s1 = 0.f, s2 = 0.f;
        for (int c = 0; c < 32; c++) {
          float wfc = src[f * 32 + c];
          s1 = fmaf(wfc, av[c], s1);
          s2 = fmaf(wfc, av[32 + c], s2);
        }
        sbuf[f] = s1;
        sbuf[32 + f] = s2;
      }
      __syncthreads();
      unsigned short* wx = Wxb + (size_t)b2 * 512;  // [col][f], 16x32
      for (int i = threadIdx.x; i < 512; i += 256) {
        int col = i >> 5, f = i & 31;
        unsigned short o = 0;
        if (col < 4) {
          float s = sbuf[(col >> 1) * 32 + f];
          unsigned short hi = f2bf_rne(s);
          o = (col & 1) ? f2bf_rne(s - bf2f(hi)) : hi;
        }
        wx[i] = o;
      }
    } else {
      int i = (b2 - 96) * 256 + threadIdx.x;
      if (i < OC * 224) mwb[i] = f2bf_rne(mw[i]);
    }
  }
}

// Fused double-hop GAT per (idx,b,t). Wh + f1/f2 via MFMA (f1/f2 through an
// extra B-frag holding hi/lo split of W@a vectors -> fp32-accurate, no shuffle
// chains); attention P@V via MFMA with per-k A-frag build (exp of masked
// lrelu), denominator via ones-B MFMA. All-masked rows -> uniform 1/200 *
// colsum(V) (JAX softmax of all -9e15). Hop1 out staged in LDS for hop2.
// NOTE on launch bounds: occupancy quantizes at 8/4/2 waves/SIMD (VGPR bins
// 64/128/256). (256,5) forced the 64-VGPR bin -> massive scratch spills
// (R6: FETCH 16->510 MB). (256,4) = 128-VGPR bin, natural ~100 VGPR, no spill.
__global__ __launch_bounds__(256, 4) void k_gat2(
    const unsigned short* __restrict__ Xb,   // (b,t,n,c) bf16 (padded alloc)
    const unsigned short* __restrict__ Wtb,  // 6 mats: [mat][b][c][f] bf16
    const unsigned short* __restrict__ Wxb,  // 6 mats: [mat][b][16][32] bf16
    const unsigned char* __restrict__ mskb,  // (b*SD+idx)*208*32 bytes
    unsigned short* __restrict__ bfp) {      // 7-tensor bf16 (b,n,t,c) pool
  int bx = blockIdx.x;
  int idx = bx / (BB * TD);
  int bt = bx % (BB * TD);
  int b = bt / TD, t = bt % TD;
  __shared__ __align__(16) unsigned short Vt[32 * 232];   // [ch][m] pad->232
  __shared__ __align__(16) unsigned short Y1s[208 * 32];  // hop1 out [n][c]
  __shared__ __align__(16) float f2s[224];
  __shared__ float f1s[208];
  __shared__ float SVa[64];   // [0..31] hop1 colsum, [32..63] hop2
  int tid = threadIdx.x, w = tid >> 6, lane = tid & 63;
  int cl = lane & 15, qd = lane >> 4;

  // ---- init pads ----
  if (tid < 64) SVa[tid] = 0.f;
  if (tid >= 200 && tid < 224) {
    f2s[tid] = 0.f;
    if (tid < 208) f1s[tid] = 0.f;
  }
  for (int i = tid; i < 512; i += 256) {  // Vt[:][200..231] = 0
    int cch = i >> 4, d = i & 15;
    ((unsigned int*)&Vt[cch * 232 + 200])[d] = 0u;
  }
  for (int i = tid; i < 128; i += 256)    // Y1s rows 200..207 = 0
    ((unsigned int*)&Y1s[200 * 32])[i] = 0u;
  __syncthreads();

  const unsigned char* mrow = mskb + (size_t)(b * SD + idx) * 208 * 32;
  bf16x8 ones;
#pragma unroll
  for (int j = 0; j < 8; j++) ones[j] = (short)0x3F80;  // bf16 1.0
  size_t xbase = (size_t)bt * SLICE;
  unsigned short* Yb1 = bfp + (size_t)(1 + 2 * idx) * TSTRIDE;
  unsigned short* Yb2 = bfp + (size_t)(2 + 2 * idx) * TSTRIDE;

#pragma unroll
  for (int hop = 0; hop < 2; hop++) {
    int mat = (hop == 0) ? idx : (3 + idx);
    const unsigned short* wtb = Wtb + (size_t)(mat * 16 + b) * 1024;
    const unsigned short* wxb = Wxb + (size_t)(mat * 16 + b) * 512;
    bf16x8 Bw0 = *(const bf16x8*)(wtb + cl * 32 + qd * 8);
    bf16x8 Bw1 = *(const bf16x8*)(wtb + (cl + 16) * 32 + qd * 8);
    bf16x8 Bwx = *(const bf16x8*)(wxb + cl * 32 + qd * 8);
    float* SV = SVa + hop * 32;

    // ---- Wh phase ----
    for (int ti = w; ti < 13; ti += 4) {
      bf16x8 A;
      if (hop == 0)
        A = *(const bf16x8*)(Xb + xbase + (size_t)(ti * 16 + cl) * 32 + qd * 8);
      else
        A = *(const bf16x8*)&Y1s[(ti * 16 + cl) * 32 + qd * 8];
      f32x4 d0 = {0.f, 0.f, 0.f, 0.f}, d1 = d0, d2 = d0;
      d0 = __builtin_amdgcn_mfma_f32_16x16x32_bf16(A, Bw0, d0, 0, 0, 0);
      d1 = __builtin_amdgcn_mfma_f32_16x16x32_bf16(A, Bw1, d1, 0, 0, 0);
      d2 = __builtin_amdgcn_mfma_f32_16x16x32_bf16(A, Bwx, d2, 0, 0, 0);
      float s0 = 0.f, s1 = 0.f;
#pragma unroll
      for (int r = 0; r < 4; r++) {
        float fv = d2[r] + __shfl_xor(d2[r], 1, 64);  // cl0:f1, cl2:f2
        int rn = ti * 16 + qd * 4 + r;
        if (rn < ND) {
          Vt[cl * 232 + rn] = f2bf(d0[r]);
          Vt[(cl + 16) * 232 + rn] = f2bf(d1[r]);
          s0 += d0[r];
          s1 += d1[r];
          if (cl == 0) f1s[rn] = fv;
          if (cl == 2) f2s[rn] = fv;
        }
      }
      atomicAdd(&SV[cl], s0);
      atomicAdd(&SV[cl + 16], s1);
    }
    __syncthreads();

    // ---- attention phase ----
    for (int ti = w; ti < 13; ti += 4) {
      int row = ti * 16 + cl;
      float f1v = f1s[row];
      const unsigned char* mrp = mrow + row * 32 + qd;
      f32x4 denom = {0.f, 0.f, 0.f, 0.f};
      f32x4 acc0 = denom, acc1 = denom;
#pragma unroll
      for (int k = 0; k < 7; k++) {
        int m0 = k * 32 + qd * 8;
        bf16x8 b0 = *(const bf16x8*)&Vt[cl * 232 + m0];
        bf16x8 b1 = *(const bf16x8*)&Vt[(cl + 16) * 232 + m0];
        float4 fa = *(const float4*)&f2s[m0];
        float4 fb = *(const float4*)&f2s[m0 + 4];
        unsigned int mby = mrp[k * 4];
        float ev[8];
        ev[0] = fa.x; ev[1] = fa.y; ev[2] = fa.z; ev[3] = fa.w;
        ev[4] = fb.x; ev[5] = fb.y; ev[6] = fb.z; ev[7] = fb.w;
        bf16x8 A;
#pragma unroll
        for (int j = 0; j < 8; j++) {
          float e = f1v + ev[j];
          e = fmaxf(e, 0.2f * e);                 // leaky_relu alpha=0.2
          e = ((mby >> j) & 1u) ? e : NEGBIG;     // mask -> exp()==0
          A[j] = (short)f2bf(__expf(e));
        }
        denom = __builtin_amdgcn_mfma_f32_16x16x32_bf16(A, ones, denom, 0, 0, 0);
        acc0 = __builtin_amdgcn_mfma_f32_16x16x32_bf16(A, b0, acc0, 0, 0, 0);
        acc1 = __builtin_amdgcn_mfma_f32_16x16x32_bf16(A, b1, acc1, 0, 0, 0);
      }
#pragma unroll
      for (int r = 0; r < 4; r++) {
        int rn = ti * 16 + qd * 4 + r;
        if (rn < ND) {
          float dn = denom[r];
          float v0, v1;
          if (dn > 0.f) {
            float iv = 1.0f / dn;
            v0 = acc0[r] * iv;
            v1 = acc1[r] * iv;
          } else {
            v0 = SV[cl] * (1.0f / ND);
            v1 = SV[cl + 16] * (1.0f / ND);
          }
          if (hop == 0) {
            v0 = (v0 > 0.f) ? v0 : __expf(v0) - 1.f;  // elu
            v1 = (v1 > 0.f) ? v1 : __expf(v1) - 1.f;
            unsigned short h0 = f2bf(v0), h1 = f2bf(v1);
            Y1s[rn * 32 + cl] = h0;
            Y1s[rn * 32 + cl + 16] = h1;
            size_t yb = ((size_t)(b * ND + rn) * TD + t) * 32;
            Yb1[yb + cl] = h0;
            Yb1[yb + cl + 16] = h1;
          } else {
            v0 = fmaxf(v0, 0.f);  // relu (== relu(elu(h)))
            v1 = fmaxf(v1, 0.f);
            size_t yb = ((size_t)(b * ND + rn) * TD + t) * 32;
            Yb2[yb + cl] = f2bf(v0);
            Yb2[yb + cl + 16] = f2bf(v1);
          }
        }
      }
    }
    if (hop == 0) __syncthreads();
  }
}

// 1x1 conv as MFMA GEMM per (b,n): OUT[t,o] = H[t,c] @ mw^T[c,o].
__global__ __launch_bounds__(192) void k_conv(
    const unsigned short* __restrict__ hb,   // 7 bf16 (b,n,t,c), stride TSTRIDE
    const unsigned short* __restrict__ mwb,  // (64,224) bf16
    const float* __restrict__ mb,
    float* __restrict__ out) {
  int bn = blockIdx.x;
  int b = bn / ND, n = bn % ND;
  int w = threadIdx.x >> 6, lane = threadIdx.x & 63;
  int cl = lane & 15, qd = lane >> 4;
  int mt = w;  // M-tile (t-range mt*16..mt*16+15)
  size_t abase = ((size_t)(b * ND + n) * TD + mt * 16 + cl) * 32 + qd * 8;
  bf16x8 A[7];
#pragma unroll
  for (int k = 0; k < 7; k++)
    A[k] = *(const bf16x8*)(hb + (size_t)k * TSTRIDE + abase);
#pragma unroll
  for (int nt = 0; nt < 4; nt++) {
    f32x4 acc = {0.f, 0.f, 0.f, 0.f};
#pragma unroll
    for (int k = 0; k < 7; k++) {
      bf16x8 bw = *(const bf16x8*)(mwb + (size_t)(nt * 16 + cl) * 224 + k * 32 + qd * 8);
      acc = __builtin_amdgcn_mfma_f32_16x16x32_bf16(A[k], bw, acc, 0, 0, 0);
    }
    int o = nt * 16 + cl;
    float bias = mb[o];
    float4 st;
    st.x = acc[0] + bias;
    st.y = acc[1] + bias;
    st.z = acc[2] + bias;
    st.w = acc[3] + bias;
    *(float4*)(out + ((size_t)(b * OC + o) * ND + n) * TD + mt * 16 + qd * 4) = st;
  }
}

extern "C" void kernel_launch(void* const* d_in, const int* in_sizes, int n_in,
                              void* d_out, int out_size, void* d_ws, size_t ws_size,
                              hipStream_t stream) {
  const float* x = (const float*)d_in[0];
  const int* support = (const int*)d_in[1];
  const float* W1 = (const float*)d_in[2];
  const float* a1 = (const float*)d_in[3];
  const float* WK = (const float*)d_in[4];
  const float* aK = (const float*)d_in[5];
  const float* mw = (const float*)d_in[6];
  const float* mb = (const float*)d_in[7];
  float* out = (float*)d_out;
  char* wsb = (char*)d_ws;
  // ws layout (bytes):
  //   Xbt bf16 (b,t,n,c) +1KB pad  @ 0            9,831,424
  //   bfp 7x bf16 (b,n,t,c)        @  9,831,424  68,812,800
  //   msk 48*208*32 B              @ 78,644,224     319,488
  //   mwb bf16                     @ 78,963,712      28,672
  //   Wtb 6*16*1024 bf16           @ 78,992,384     196,608
  //   Wxb 6*16*512  bf16           @ 79,188,992      98,304   => ~79.3 MB
  unsigned short* Xbt = (unsigned short*)wsb;
  unsigned short* bfp = (unsigned short*)(wsb + 9831424);
  unsigned char* msk = (unsigned char*)(wsb + 78644224);
  unsigned short* mwb = (unsigned short*)(wsb + 78963712);
  unsigned short* Wtb = (unsigned short*)(wsb + 78992384);
  unsigned short* Wxb = (unsigned short*)(wsb + 79188992);

  k_prep<<<3976, 256, 0, stream>>>(x, support, W1, WK, a1, aK, mw, Xbt, bfp,
                                   (unsigned long long*)msk, Wtb, Wxb, mwb);
  k_gat2<<<SD * BB * TD, 256, 0, stream>>>(Xbt, Wtb, Wxb, msk, bfp);
  k_conv<<<BB * ND, 192, 0, stream>>>(bfp, mwb, mb, out);
}

// Round 8
// 264.326 us; speedup vs baseline: 1.4843x; 1.2038x over previous
//
#include <hip/hip_runtime.h>
#include <math.h>

// ---- problem constants ----
#define BB 16
#define FD 32          // F == C == 32
#define ND 200
#define TD 48
#define SD 3
#define OC 64
#define SLICE 6400            // N*C elements per (b,t)
#define TSTRIDE 4915200       // B*T*N*C elements per tensor
#define NEGBIG (-9.0e15f)

typedef __attribute__((ext_vector_type(8))) short bf16x8;
typedef __attribute__((ext_vector_type(4))) float f32x4;

// round-half-up bf16 (within 1 ulp of RNE, 1 VALU op + shift)
static __device__ __forceinline__ unsigned short f2bf(float f) {
  unsigned u = __builtin_bit_cast(unsigned, f);
  return (unsigned short)((u + 0x8000u) >> 16);
}
// exact RNE (used for hi/lo weight split so the residual is well-defined)
static __device__ __forceinline__ unsigned short f2bf_rne(float f) {
  unsigned u = __builtin_bit_cast(unsigned, f);
  return (unsigned short)((u + 0x7FFFu + ((u >> 16) & 1u)) >> 16);
}
static __device__ __forceinline__ float bf2f(unsigned short h) {
  unsigned u = ((unsigned)h) << 16;
  return __builtin_bit_cast(float, u);
}

// One prep launch, three block ranges:
//   [0,3200):      x (b,f,n,t) fp32 -> Xtnc (b,t,n,c) bf16 + Xntc (b,n,t,c) bf16
//   [3200,3824):   adjacency -> permuted 200-bit row masks: per row 4 u64,
//                  qword qd holds bytes [k=0..6] = adjacency bits for
//                  m = k*32 + qd*8 + j  (one u64 load per 16-row tile later)
//   [3824,3976):   W transpose->bf16, w-vector hi/lo frags, mlp_w -> bf16
__global__ __launch_bounds__(256) void k_prep(
    const float* __restrict__ x, const int* __restrict__ support,
    const float* __restrict__ W1, const float* __restrict__ WK,
    const float* __restrict__ a1, const float* __restrict__ aK,
    const float* __restrict__ mw,
    unsigned short* __restrict__ Xtnc, unsigned short* __restrict__ Xntc,
    unsigned long long* __restrict__ msk,
    unsigned short* __restrict__ Wtb, unsigned short* __restrict__ Wxb,
    unsigned short* __restrict__ mwb) {
  __shared__ float sbuf[32 * 49];
  int bid = blockIdx.x;
  if (bid < 3200) {
    int b = bid / ND, n = bid % ND;
    float(*sf)[49] = (float(*)[49])sbuf;
    for (int i = threadIdx.x; i < 32 * 48; i += 256) {
      int f = i / 48, t = i % 48;
      sf[f][t] = x[((size_t)(b * 32 + f) * ND + n) * 48 + t];
    }
    __syncthreads();
    unsigned int* dt = (unsigned int*)Xtnc;
    unsigned int* dn = (unsigned int*)Xntc;
    for (int j = threadIdx.x; j < 768; j += 256) {
      int t = j >> 4, fq = j & 15;
      unsigned int v = (unsigned int)f2bf(sf[2 * fq][t]) |
                       ((unsigned int)f2bf(sf[2 * fq + 1][t]) << 16);
      dt[((size_t)(b * 48 + t) * ND + n) * 16 + fq] = v;
      dn[((size_t)(b * ND + n) * 48 + t) * 16 + fq] = v;
    }
  } else if (bid < 3824) {
    int q = bid - 3200;
    int si = q / 13, rg = q % 13;
    const int* adjb = support + (size_t)si * ND * ND;
    int wv = threadIdx.x >> 6, lane = threadIdx.x & 63;
#pragma unroll
    for (int j = 0; j < 4; j++) {
      int r = rg * 16 + wv * 4 + j;
      unsigned long long ws0 = 0, ws1 = 0, ws2 = 0, ws3 = 0;
      if (r < ND) {
        ws0 = __ballot(adjb[r * ND + lane] > 0);
        ws1 = __ballot(adjb[r * ND + 64 + lane] > 0);
        ws2 = __ballot(((128 + lane < ND) ? adjb[r * ND + 128 + lane] : 0) > 0);
        ws3 = __ballot(((192 + lane < ND) ? adjb[r * ND + 192 + lane] : 0) > 0);
      }
      // permute bytes: output qword qd, byte k  <-  straight byte (k*4+qd)
      if (lane < 4 && r < 208) {
        unsigned long long o = 0;
#pragma unroll
        for (int k = 0; k < 7; k++) {
          int bidx = k * 4 + lane;
          int sel = bidx >> 3;
          unsigned long long src = (sel == 0) ? ws0 : (sel == 1) ? ws1
                                 : (sel == 2) ? ws2 : ws3;
          unsigned long long byte = (src >> ((bidx & 7) * 8)) & 0xFFull;
          o |= byte << (8 * k);
        }
        msk[((size_t)si * 208 + r) * 4 + lane] = o;
      }
    }
  } else {
    int b2 = bid - 3824;
    if (b2 < 96) {
      int mat = b2 >> 4, b = b2 & 15;
      const float* src = (mat < 3) ? (W1 + (size_t)(mat * 16 + b) * 1024)
                                   : (WK + (size_t)((mat - 3) * 16 + b) * 1024);
      const float* av = (mat < 3) ? (a1 + (size_t)mat * 1024 + b * 64)
                                  : (aK + (size_t)(mat - 3) * 1024 + b * 64);
      unsigned short* dst = Wtb + (size_t)b2 * 1024;
      for (int i = threadIdx.x; i < 1024; i += 256) {
        int c = i >> 5, f = i & 31;
        dst[c * 32 + f] = f2bf_rne(src[f * 32 + c]);
      }
      // w-vectors: w1 = W@a1cols, w2 = W@a2cols (fp32), hi/lo bf16 split
      if (threadIdx.x < 32) {
        int f = threadIdx.x;
        float s1 = 0.f, s2 = 0.f;
        for (int c = 0; c < 32; c++) {
          float wfc = src[f * 32 + c];
          s1 = fmaf(wfc, av[c], s1);
          s2 = fmaf(wfc, av[32 + c], s2);
        }
        sbuf[f] = s1;
        sbuf[32 + f] = s2;
      }
      __syncthreads();
      unsigned short* wx = Wxb + (size_t)b2 * 512;  // [col][f], 16x32
      for (int i = threadIdx.x; i < 512; i += 256) {
        int col = i >> 5, f = i & 31;
        unsigned short o = 0;
        if (col < 4) {
          float s = sbuf[(col >> 1) * 32 + f];
          unsigned short hi = f2bf_rne(s);
          o = (col & 1) ? f2bf_rne(s - bf2f(hi)) : hi;
        }
        wx[i] = o;
      }
    } else {
      int i = (b2 - 96) * 256 + threadIdx.x;
      if (i < OC * 224) mwb[i] = f2bf_rne(mw[i]);
    }
  }
}

// Fused double-hop GAT per (idx,b,t). Wh + f1/f2 via MFMA (f1/f2 through an
// extra B-frag holding hi/lo split of W@a vectors -> fp32-accurate); attention
// P@V via MFMA with per-k A-frag build (exp of masked lrelu), denominator via
// ones-B MFMA. All-masked rows -> uniform 1/200 * colsum(V) (JAX softmax of
// all -9e15). Hop1 out staged in LDS for hop2.
// NOTE: no 2nd __launch_bounds__ arg! On this toolchain it makes the
// allocator spill to chase a higher occupancy bin (R6: (256,5)->48 VGPR,
// 940 MB HBM spill; R7: (256,4)->64 VGPR, 450 MB). Default alloc: ~104 VGPR,
// zero spill, 4 waves/SIMD (the only reachable bin: steps are 64/128/256).
__global__ __launch_bounds__(256) void k_gat2(
    const unsigned short* __restrict__ Xb,   // (b,t,n,c) bf16 (padded alloc)
    const unsigned short* __restrict__ Wtb,  // 6 mats: [mat][b][c][f] bf16
    const unsigned short* __restrict__ Wxb,  // 6 mats: [mat][b][16][32] bf16
    const unsigned char* __restrict__ mskb,  // (b*SD+idx)*208*32 B, permuted
    unsigned short* __restrict__ bfp) {      // 7-tensor bf16 (b,n,t,c) pool
  int bx = blockIdx.x;
  int idx = bx / (BB * TD);
  int bt = bx % (BB * TD);
  int b = bt / TD, t = bt % TD;
  __shared__ __align__(16) unsigned short Vt[32 * 232];   // [ch][m] pad->232
  __shared__ __align__(16) unsigned short Y1s[208 * 32];  // hop1 out [n][c]
  __shared__ __align__(16) float f2s[224];
  __shared__ float f1s[208];
  __shared__ float SVa[64];   // [0..31] hop1 colsum, [32..63] hop2
  int tid = threadIdx.x, w = tid >> 6, lane = tid & 63;
  int cl = lane & 15, qd = lane >> 4;

  // ---- init pads ----
  if (tid < 64) SVa[tid] = 0.f;
  if (tid >= 200 && tid < 224) {
    f2s[tid] = 0.f;
    if (tid < 208) f1s[tid] = 0.f;
  }
  for (int i = tid; i < 512; i += 256) {  // Vt[:][200..231] = 0
    int cch = i >> 4, d = i & 15;
    ((unsigned int*)&Vt[cch * 232 + 200])[d] = 0u;
  }
  for (int i = tid; i < 128; i += 256)    // Y1s rows 200..207 = 0
    ((unsigned int*)&Y1s[200 * 32])[i] = 0u;
  __syncthreads();

  const unsigned char* mrow = mskb + (size_t)(b * SD + idx) * 208 * 32;
  bf16x8 ones;
#pragma unroll
  for (int j = 0; j < 8; j++) ones[j] = (short)0x3F80;  // bf16 1.0
  size_t xbase = (size_t)bt * SLICE;
  unsigned short* Yb1 = bfp + (size_t)(1 + 2 * idx) * TSTRIDE;
  unsigned short* Yb2 = bfp + (size_t)(2 + 2 * idx) * TSTRIDE;

#pragma unroll
  for (int hop = 0; hop < 2; hop++) {
    int mat = (hop == 0) ? idx : (3 + idx);
    const unsigned short* wtb = Wtb + (size_t)(mat * 16 + b) * 1024;
    const unsigned short* wxb = Wxb + (size_t)(mat * 16 + b) * 512;
    bf16x8 Bw0 = *(const bf16x8*)(wtb + cl * 32 + qd * 8);
    bf16x8 Bw1 = *(const bf16x8*)(wtb + (cl + 16) * 32 + qd * 8);
    bf16x8 Bwx = *(const bf16x8*)(wxb + cl * 32 + qd * 8);
    float* SV = SVa + hop * 32;

    // ---- Wh phase ----
    for (int ti = w; ti < 13; ti += 4) {
      bf16x8 A;
      if (hop == 0)
        A = *(const bf16x8*)(Xb + xbase + (size_t)(ti * 16 + cl) * 32 + qd * 8);
      else
        A = *(const bf16x8*)&Y1s[(ti * 16 + cl) * 32 + qd * 8];
      f32x4 d0 = {0.f, 0.f, 0.f, 0.f}, d1 = d0, d2 = d0;
      d0 = __builtin_amdgcn_mfma_f32_16x16x32_bf16(A, Bw0, d0, 0, 0, 0);
      d1 = __builtin_amdgcn_mfma_f32_16x16x32_bf16(A, Bw1, d1, 0, 0, 0);
      d2 = __builtin_amdgcn_mfma_f32_16x16x32_bf16(A, Bwx, d2, 0, 0, 0);
      float s0 = 0.f, s1 = 0.f;
#pragma unroll
      for (int r = 0; r < 4; r++) {
        float fv = d2[r] + __shfl_xor(d2[r], 1, 64);  // cl0:f1, cl2:f2
        int rn = ti * 16 + qd * 4 + r;
        if (rn < ND) {
          Vt[cl * 232 + rn] = f2bf(d0[r]);
          Vt[(cl + 16) * 232 + rn] = f2bf(d1[r]);
          s0 += d0[r];
          s1 += d1[r];
          if (cl == 0) f1s[rn] = fv;
          if (cl == 2) f2s[rn] = fv;
        }
      }
      atomicAdd(&SV[cl], s0);
      atomicAdd(&SV[cl + 16], s1);
    }
    __syncthreads();

    // ---- attention phase ----
    for (int ti = w; ti < 13; ti += 4) {
      int row = ti * 16 + cl;
      float f1v = f1s[row];
      // one u64: byte k = adjacency bits for m = k*32 + qd*8 + j
      const unsigned long long mq =
          *(const unsigned long long*)(mrow + (size_t)row * 32 + qd * 8);
      f32x4 denom = {0.f, 0.f, 0.f, 0.f};
      f32x4 acc0 = denom, acc1 = denom;
#pragma unroll
      for (int k = 0; k < 7; k++) {
        int m0 = k * 32 + qd * 8;
        bf16x8 b0 = *(const bf16x8*)&Vt[cl * 232 + m0];
        bf16x8 b1 = *(const bf16x8*)&Vt[(cl + 16) * 232 + m0];
        float4 fa = *(const float4*)&f2s[m0];
        float4 fb = *(const float4*)&f2s[m0 + 4];
        unsigned int mby = (unsigned int)(mq >> (8 * k)) & 0xFFu;
        float ev[8];
        ev[0] = fa.x; ev[1] = fa.y; ev[2] = fa.z; ev[3] = fa.w;
        ev[4] = fb.x; ev[5] = fb.y; ev[6] = fb.z; ev[7] = fb.w;
        bf16x8 A;
#pragma unroll
        for (int j = 0; j < 8; j++) {
          float e = f1v + ev[j];
          e = fmaxf(e, 0.2f * e);                 // leaky_relu alpha=0.2
          e = ((mby >> j) & 1u) ? e : NEGBIG;     // mask -> exp()==0
          A[j] = (short)f2bf(__expf(e));
        }
        denom = __builtin_amdgcn_mfma_f32_16x16x32_bf16(A, ones, denom, 0, 0, 0);
        acc0 = __builtin_amdgcn_mfma_f32_16x16x32_bf16(A, b0, acc0, 0, 0, 0);
        acc1 = __builtin_amdgcn_mfma_f32_16x16x32_bf16(A, b1, acc1, 0, 0, 0);
      }
#pragma unroll
      for (int r = 0; r < 4; r++) {
        int rn = ti * 16 + qd * 4 + r;
        if (rn < ND) {
          float dn = denom[r];
          float v0, v1;
          if (dn > 0.f) {
            float iv = 1.0f / dn;
            v0 = acc0[r] * iv;
            v1 = acc1[r] * iv;
          } else {
            v0 = SV[cl] * (1.0f / ND);
            v1 = SV[cl + 16] * (1.0f / ND);
          }
          if (hop == 0) {
            v0 = (v0 > 0.f) ? v0 : __expf(v0) - 1.f;  // elu
            v1 = (v1 > 0.f) ? v1 : __expf(v1) - 1.f;
            unsigned short h0 = f2bf(v0), h1 = f2bf(v1);
            Y1s[rn * 32 + cl] = h0;
            Y1s[rn * 32 + cl + 16] = h1;
            size_t yb = ((size_t)(b * ND + rn) * TD + t) * 32;
            Yb1[yb + cl] = h0;
            Yb1[yb + cl + 16] = h1;
          } else {
            v0 = fmaxf(v0, 0.f);  // relu (== relu(elu(h)))
            v1 = fmaxf(v1, 0.f);
            size_t yb = ((size_t)(b * ND + rn) * TD + t) * 32;
            Yb2[yb + cl] = f2bf(v0);
            Yb2[yb + cl + 16] = f2bf(v1);
          }
        }
      }
    }
    if (hop == 0) __syncthreads();
  }
}

// 1x1 conv as MFMA GEMM per (b,n): OUT[t,o] = H[t,c] @ mw^T[c,o].
__global__ __launch_bounds__(192) void k_conv(
    const unsigned short* __restrict__ hb,   // 7 bf16 (b,n,t,c), stride TSTRIDE
    const unsigned short* __restrict__ mwb,  // (64,224) bf16
    const float* __restrict__ mb,
    float* __restrict__ out) {
  int bn = blockIdx.x;
  int b = bn / ND, n = bn % ND;
  int w = threadIdx.x >> 6, lane = threadIdx.x & 63;
  int cl = lane & 15, qd = lane >> 4;
  int mt = w;  // M-tile (t-range mt*16..mt*16+15)
  size_t abase = ((size_t)(b * ND + n) * TD + mt * 16 + cl) * 32 + qd * 8;
  bf16x8 A[7];
#pragma unroll
  for (int k = 0; k < 7; k++)
    A[k] = *(const bf16x8*)(hb + (size_t)k * TSTRIDE + abase);
#pragma unroll
  for (int nt = 0; nt < 4; nt++) {
    f32x4 acc = {0.f, 0.f, 0.f, 0.f};
#pragma unroll
    for (int k = 0; k < 7; k++) {
      bf16x8 bw = *(const bf16x8*)(mwb + (size_t)(nt * 16 + cl) * 224 + k * 32 + qd * 8);
      acc = __builtin_amdgcn_mfma_f32_16x16x32_bf16(A[k], bw, acc, 0, 0, 0);
    }
    int o = nt * 16 + cl;
    float bias = mb[o];
    float4 st;
    st.x = acc[0] + bias;
    st.y = acc[1] + bias;
    st.z = acc[2] + bias;
    st.w = acc[3] + bias;
    *(float4*)(out + ((size_t)(b * OC + o) * ND + n) * TD + mt * 16 + qd * 4) = st;
  }
}

extern "C" void kernel_launch(void* const* d_in, const int* in_sizes, int n_in,
                              void* d_out, int out_size, void* d_ws, size_t ws_size,
                              hipStream_t stream) {
  const float* x = (const float*)d_in[0];
  const int* support = (const int*)d_in[1];
  const float* W1 = (const float*)d_in[2];
  const float* a1 = (const float*)d_in[3];
  const float* WK = (const float*)d_in[4];
  const float* aK = (const float*)d_in[5];
  const float* mw = (const float*)d_in[6];
  const float* mb = (const float*)d_in[7];
  float* out = (float*)d_out;
  char* wsb = (char*)d_ws;
  // ws layout (bytes):
  //   Xbt bf16 (b,t,n,c) +1KB pad  @ 0            9,831,424
  //   bfp 7x bf16 (b,n,t,c)        @  9,831,424  68,812,800
  //   msk 48*208*32 B              @ 78,644,224     319,488
  //   mwb bf16                     @ 78,963,712      28,672
  //   Wtb 6*16*1024 bf16           @ 78,992,384     196,608
  //   Wxb 6*16*512  bf16           @ 79,188,992      98,304   => ~79.3 MB
  unsigned short* Xbt = (unsigned short*)wsb;
  unsigned short* bfp = (unsigned short*)(wsb + 9831424);
  unsigned char* msk = (unsigned char*)(wsb + 78644224);
  unsigned short* mwb = (unsigned short*)(wsb + 78963712);
  unsigned short* Wtb = (unsigned short*)(wsb + 78992384);
  unsigned short* Wxb = (unsigned short*)(wsb + 79188992);

  k_prep<<<3976, 256, 0, stream>>>(x, support, W1, WK, a1, aK, mw, Xbt, bfp,
                                   (unsigned long long*)msk, Wtb, Wxb, mwb);
  k_gat2<<<SD * BB * TD, 256, 0, stream>>>(Xbt, Wtb, Wxb, msk, bfp);
  k_conv<<<BB * ND, 192, 0, stream>>>(bfp, mwb, mb, out);
}